// Round 1
// baseline (131.116 us; speedup 1.0000x reference)
//
#include <hip/hip_runtime.h>

// DCN CrossLayer: B=16384, F=1024, L=3, fp32.
// Algebraic expansion of the 3-layer recurrence (verified against reference):
//   d_j  = x0 . w_j    (per-row)       t01=b0.w1  t02=b0.w2  t12=b1.w2 (global)
//   a1 = 1+d0;  s1 = a1*d1 + t01;  a2 = a1+s1;  s2 = a2*d2 + t02+t12
//   out = x0*(a2+s2) + (b0+b1+b2)
//
// v2: 4 rows per wave. The kernel is vec-mem-INSTRUCTION bound, not byte
// bound: v1 issued 40 float4 mem insts + 36 shuffle-adds per row vs the 8
// insts of mandatory HBM traffic. Processing 4 rows/wave amortizes the
// broadcast w/b loads and the 6-step butterfly 4x:
//   mem inst/row 40 -> 18, shuffle-adds/row 36 -> ~23.
// x is read exactly once and held in registers (64 VGPR/lane); the single
// interleaved 15-value butterfly (12 row-dots + 3 t-terms) pays DS latency
// once per 4 rows. t-terms computed in a separate small loop (w1/w2/b0/b1
// re-read from L1) to keep main-loop register pressure under the 128-VGPR
// cap from __launch_bounds__(256,4) -> 4 waves/SIMD, all 4096 waves
// co-resident (1024 blocks x 4 waves), zero tail.

constexpr int B = 16384;
constexpr int F = 1024;                 // 256 float4 per row = 4 chunks of 64 lanes
constexpr int ROWS_PER_WAVE = 4;
constexpr int WAVES = 4;
constexpr int ROWS_PER_BLOCK = ROWS_PER_WAVE * WAVES;  // 16
constexpr int BLOCK = 64 * WAVES;       // 256 threads

__global__ __launch_bounds__(BLOCK, 4) void cross_layer_kernel(
    const float* __restrict__ x,        // [B, F]
    const float* __restrict__ kernels,  // [3, F]
    const float* __restrict__ bias,     // [3, F]
    float* __restrict__ out)            // [B, F]
{
    const int lane = threadIdx.x & 63;
    const int wave = threadIdx.x >> 6;
    const int row0 = blockIdx.x * ROWS_PER_BLOCK + wave * ROWS_PER_WAVE;

    const float4* w0v = (const float4*)(kernels);
    const float4* w1v = (const float4*)(kernels + F);
    const float4* w2v = (const float4*)(kernels + 2 * F);
    const float4* b0v = (const float4*)(bias);
    const float4* b1v = (const float4*)(bias + F);
    const float4* b2v = (const float4*)(bias + 2 * F);

    // Front-load 4 x rows (16 coalesced 16B loads; x read exactly once).
    float4 xr[ROWS_PER_WAVE][4];
#pragma unroll
    for (int r = 0; r < ROWS_PER_WAVE; ++r) {
        const float4* xrow = (const float4*)(x + (size_t)(row0 + r) * F);
#pragma unroll
        for (int c = 0; c < 4; ++c) xr[r][c] = xrow[c * 64 + lane];
    }

    // Per-row dot partials d[r][j] = x_r . w_j (12 accumulators).
    float d[ROWS_PER_WAVE][3];
#pragma unroll
    for (int r = 0; r < ROWS_PER_WAVE; ++r)
        d[r][0] = d[r][1] = d[r][2] = 0.f;

#pragma unroll
    for (int c = 0; c < 4; ++c) {
        const int i = c * 64 + lane;
        const float4 w0 = w0v[i];
        const float4 w1 = w1v[i];
        const float4 w2 = w2v[i];
#pragma unroll
        for (int r = 0; r < ROWS_PER_WAVE; ++r) {
            const float4 xv = xr[r][c];
            d[r][0] = fmaf(xv.x, w0.x, d[r][0]);
            d[r][0] = fmaf(xv.y, w0.y, d[r][0]);
            d[r][0] = fmaf(xv.z, w0.z, d[r][0]);
            d[r][0] = fmaf(xv.w, w0.w, d[r][0]);

            d[r][1] = fmaf(xv.x, w1.x, d[r][1]);
            d[r][1] = fmaf(xv.y, w1.y, d[r][1]);
            d[r][1] = fmaf(xv.z, w1.z, d[r][1]);
            d[r][1] = fmaf(xv.w, w1.w, d[r][1]);

            d[r][2] = fmaf(xv.x, w2.x, d[r][2]);
            d[r][2] = fmaf(xv.y, w2.y, d[r][2]);
            d[r][2] = fmaf(xv.z, w2.z, d[r][2]);
            d[r][2] = fmaf(xv.w, w2.w, d[r][2]);
        }
    }

    // Row-independent bias-kernel dot partials (separate loop keeps the
    // main loop's transient register set to just w0/w1/w2; these loads are
    // L1-resident re-reads).
    float t01 = 0.f, t02 = 0.f, t12 = 0.f;
#pragma unroll
    for (int c = 0; c < 4; ++c) {
        const int i = c * 64 + lane;
        const float4 w1 = w1v[i];
        const float4 w2 = w2v[i];
        const float4 b0 = b0v[i];
        const float4 b1 = b1v[i];
        t01 = fmaf(b0.x, w1.x, t01); t01 = fmaf(b0.y, w1.y, t01);
        t01 = fmaf(b0.z, w1.z, t01); t01 = fmaf(b0.w, w1.w, t01);
        t02 = fmaf(b0.x, w2.x, t02); t02 = fmaf(b0.y, w2.y, t02);
        t02 = fmaf(b0.z, w2.z, t02); t02 = fmaf(b0.w, w2.w, t02);
        t12 = fmaf(b1.x, w2.x, t12); t12 = fmaf(b1.y, w2.y, t12);
        t12 = fmaf(b1.z, w2.z, t12); t12 = fmaf(b1.w, w2.w, t12);
    }

    // Single interleaved 15-value butterfly: 12 row-dots + 3 t-terms.
    // All 15 shuffles per step are independent -> DS latency paid ~once/step,
    // and the whole reduction is amortized over 4 rows.
    float p[15] = { d[0][0], d[0][1], d[0][2],
                    d[1][0], d[1][1], d[1][2],
                    d[2][0], d[2][1], d[2][2],
                    d[3][0], d[3][1], d[3][2],
                    t01, t02, t12 };
#pragma unroll
    for (int off = 32; off >= 1; off >>= 1) {
#pragma unroll
        for (int k = 0; k < 15; ++k) p[k] += __shfl_xor(p[k], off, 64);
    }

    // Scalar recurrences (all lanes hold the full sums).
    const float tsum = p[13] + p[14];   // t02 + t12
    float S[ROWS_PER_WAVE];
#pragma unroll
    for (int r = 0; r < ROWS_PER_WAVE; ++r) {
        const float a1 = 1.f + p[3 * r + 0];
        const float s1 = fmaf(a1, p[3 * r + 1], p[12]);
        const float a2 = a1 + s1;
        const float s2 = fmaf(a2, p[3 * r + 2], tsum);
        S[r] = a2 + s2;
    }

    // Epilogue: out = x0*S + (b0+b1+b2). b re-read once per wave (L1-hit),
    // bias sum shared across the 4 rows.
#pragma unroll
    for (int c = 0; c < 4; ++c) {
        const int i = c * 64 + lane;
        const float4 b0 = b0v[i];
        const float4 b1 = b1v[i];
        const float4 b2 = b2v[i];
        float4 bs;
        bs.x = b0.x + b1.x + b2.x;
        bs.y = b0.y + b1.y + b2.y;
        bs.z = b0.z + b1.z + b2.z;
        bs.w = b0.w + b1.w + b2.w;
#pragma unroll
        for (int r = 0; r < ROWS_PER_WAVE; ++r) {
            float4 o;
            o.x = fmaf(xr[r][c].x, S[r], bs.x);
            o.y = fmaf(xr[r][c].y, S[r], bs.y);
            o.z = fmaf(xr[r][c].z, S[r], bs.z);
            o.w = fmaf(xr[r][c].w, S[r], bs.w);
            ((float4*)(out + (size_t)(row0 + r) * F))[i] = o;
        }
    }
}

extern "C" void kernel_launch(void* const* d_in, const int* in_sizes, int n_in,
                              void* d_out, int out_size, void* d_ws, size_t ws_size,
                              hipStream_t stream) {
    const float* x       = (const float*)d_in[0];
    const float* kernels = (const float*)d_in[1];
    const float* bias    = (const float*)d_in[2];
    float* out           = (float*)d_out;

    dim3 grid(B / ROWS_PER_BLOCK);  // 1024 blocks
    dim3 block(BLOCK);              // 256 threads = 4 waves
    cross_layer_kernel<<<grid, block, 0, stream>>>(x, kernels, bias, out);
}